// Round 7
// baseline (194.944 us; speedup 1.0000x reference)
//
#include <hip/hip_runtime.h>

#define B_ 512
#define T_ 512
#define C_ 128
#define L_ 80
#define BLANK_ 127
#define EPS_ 1e-7f
#define LN2_ 0.6931471805599453f

// raw v_log_f32 (base-2); __log2f collides with glibc math.h reserved names.
#define LOG2F(x) __builtin_amdgcn_logf(x)

// DPP cross-lane ops (VALU pipe — DS pipe stays off the critical path).
template <int CTRL> __device__ __forceinline__ int dpp_i(int x) {
  return __builtin_amdgcn_update_dpp(0, x, CTRL, 0xF, 0xF, true);
}
template <int CTRL> __device__ __forceinline__ float dpp_f(float x) {
  return __int_as_float(
      __builtin_amdgcn_update_dpp(0, __float_as_int(x), CTRL, 0xF, 0xF, true));
}
#define DPP_WSHR1 0x138   // wave shift right 1 (lane0 -> 0 via bound_ctrl)
#define DPP_XOR1  0xB1    // quad_perm lane^1
#define DPP_XOR2  0x4E    // quad_perm lane^2
#define DPP_HMIRR 0x141   // row_half_mirror (within 8)
#define DPP_MIRR  0x140   // row_mirror (within 16)

// One wave per batch. Lane i owns extended states 3i..3i+2. Linear-prob DP
// (alpha_new = q*(a0+a1+m*a2)) with per-lane exponent E, rescaled per 8-step
// block. 6-deep global prefetch + double-buffered LDS gathers. Per block only
// 16 ds_read_b32 (primary + secondary label gathers); the blank column p[127]
// is extracted at staging time via v_readlane into wave-uniform values (no DS).
// __launch_bounds__(64,1): min 1 wave/EU -> full VGPR budget, no spill.
__global__ __launch_bounds__(64, 1) void ctc_fused(
    const int* __restrict__ labels,     // [B,L]
    const float* __restrict__ y_pred,   // [B,T,C]
    float* __restrict__ out)            // [B,1]
{
  const int b = blockIdx.x, lane = threadIdx.x;
  const float4* rp = (const float4*)(y_pred + (size_t)b * T_ * C_);
  __shared__ float ring[2 * 8 * C_];    // 2 banks x 8 rows x 128 floats

  const int rgrp = lane >> 3, j16 = lane & 7;
  const bool evn = ((lane & 1) == 0);

  auto labAt = [&](int k) -> int {
    return (k >= 0 && k < L_) ? labels[b * L_ + k] : BLANK_;
  };
  // Gather symbols: xp = primary label (even lane: its center label; odd lane:
  // its first label), xs = secondary (even: BLANK -> blank value; odd: 2nd
  // label). Skip masks m0..m2 as 0/1 floats.
  int xp, xs; float m0, m1, m2;
  if (evn) {                             // states: blank / label k1 / blank
    const int k1 = (3 * lane) >> 1;
    const int e = labAt(k1);
    xp = e; xs = BLANK_;
    m0 = 0.f; m2 = 0.f;
    m1 = ((k1 < L_) && (k1 == 0 || e != labAt(k1 - 1))) ? 1.f : 0.f;
  } else {                               // states: label k0 / blank / label k2
    const int k0 = (3 * lane - 1) >> 1, k2 = k0 + 1;
    const int ea = labAt(k0), eb = labAt(k2);
    xp = ea; xs = eb;
    m0 = ((k0 < L_) && (k0 == 0 || ea != labAt(k0 - 1))) ? 1.f : 0.f;
    m1 = 0.f;
    m2 = ((k2 < L_) && (eb != ea)) ? 1.f : 0.f;
  }

  float Sacc = 0.f;
  float A0, A1, A2; int E = 0;

  auto gload = [&](float4 (&S)[4], int blk) {
    int row = blk * 8 + rgrp; if (row > T_ - 1) row = T_ - 1;
    const float4* src = rp + row * 32 + 4 * j16;
    #pragma unroll
    for (int k = 0; k < 4; ++k) S[k] = src[k];
  };
  // eps-add, stage to ring bank, fused row-sum (DPP reduce) + log2, and
  // extract blank column p[127]+eps per row via readlane (element 127 of row
  // j lives in lane 8j+7's Sw[3].w).
  auto prep = [&](float4 (&Sw)[4], int bankDst, float (&bl)[8]) {
    #pragma unroll
    for (int k = 0; k < 4; ++k) {
      Sw[k].x += EPS_; Sw[k].y += EPS_; Sw[k].z += EPS_; Sw[k].w += EPS_;
    }
    float4* wd = (float4*)(ring + bankDst * 1024 + rgrp * C_ + 16 * j16);
    #pragma unroll
    for (int k = 0; k < 4; ++k) wd[k] = Sw[k];
    float s = 0.f;
    #pragma unroll
    for (int k = 0; k < 4; ++k) s += (Sw[k].x + Sw[k].y) + (Sw[k].z + Sw[k].w);
    s += dpp_f<DPP_XOR1>(s);
    s += dpp_f<DPP_XOR2>(s);
    s += dpp_f<DPP_HMIRR>(s);
    Sacc += LOG2F(s);                   // 8x redundant per row; /8 at the end
    #pragma unroll
    for (int j = 0; j < 8; ++j)
      bl[j] = __int_as_float(
          __builtin_amdgcn_readlane(__float_as_int(Sw[3].w), 8 * j + 7));
  };
  auto gath = [&](float (&r1)[8], float (&r2)[8], int bank) {
    const float* rb = ring + bank * 1024;
    #pragma unroll
    for (int j = 0; j < 8; ++j) {
      r1[j] = rb[j * C_ + xp];
      r2[j] = rb[j * C_ + xs];
    }
  };
  auto dp8 = [&](float (&r1)[8], float (&r2)[8], float (&bl)[8]) {
    const int EL = dpp_i<DPP_WSHR1>(E);
    const int d = E - EL;               // block-constant reconcile shift
    #pragma unroll
    for (int j = 0; j < 8; ++j) {
      const float p1 = dpp_f<DPP_WSHR1>(A1);   // left A1 (state 3i-2)
      const float p2 = dpp_f<DPP_WSHR1>(A2);   // left A2 (state 3i-1)
      const float p1p = ldexpf(p1, d);
      const float p2p = ldexpf(p2, d);
      const float q0 = evn ? r2[j] : r1[j];    // even: blank, odd: label k0
      const float q1 = evn ? r1[j] : bl[j];    // even: label, odd: blank
      const float q2 = r2[j];                  // even: blank, odd: label k2
      const float t0 = q0 * fmaf(m0, p1p, A0 + p2p);
      const float t1 = q1 * fmaf(m1, p2p, A1 + A0);
      const float t2 = q2 * fmaf(m2, A0, A2 + A1);
      A0 = t0; A1 = t1; A2 = t2;
    }
    // per-lane rescale: fold lane max exponent into E
    const float mx = fmaxf(fmaxf(A0, A1), A2);
    int ee = (int)((__float_as_uint(mx) >> 23) & 255u) - 127;
    const bool z = (mx == 0.f);
    ee = z ? 0 : ee;
    A0 = ldexpf(A0, -ee); A1 = ldexpf(A1, -ee); A2 = ldexpf(A2, -ee);
    E = z ? EL : (E - ee);              // virgin lanes track left neighbor
  };

  // ---- prologue: sets 0..5 <- blocks 0..5; stage+gather block 0; S0 <- 6 ----
  float4 S0[4], S1[4], S2[4], S3[4], S4[4], S5[4];
  gload(S0, 0); gload(S1, 1); gload(S2, 2);
  gload(S3, 3); gload(S4, 4); gload(S5, 5);
  float r1b[2][8], r2b[2][8], blb[2][8];
  prep(S0, 0, blb[0]);
  gath(r1b[0], r2b[0], 0);
  gload(S0, 6);
  // virtual init: one DP step from (A0=1@lane0) yields exact alpha(t=0)
  A0 = (lane == 0) ? 1.f : 0.f; A1 = 0.f; A2 = 0.f;

  // body(n): stage block n+1 (bank (n+1)&1) + extract its blanks, issue its
  // gathers (consumed next body), reload freed set with block n+7, then run
  // 8 DP steps of block n on gathers issued last body.
  auto body = [&](int n, float4 (&Sst)[4], int cur, int nxt, bool doStage) {
    if (doStage) {
      const int bk = (n + 1) & 1;
      prep(Sst, bk, blb[nxt]);
      gath(r1b[nxt], r2b[nxt], bk);
      gload(Sst, n + 7);
    }
    dp8(r1b[cur], r2b[cur], blb[cur]);
  };

  for (int nn = 0; nn < 54; nn += 6) {
    body(nn + 0, S1, 0, 1, true);
    body(nn + 1, S2, 1, 0, true);
    body(nn + 2, S3, 0, 1, true);
    body(nn + 3, S4, 1, 0, true);
    body(nn + 4, S5, 0, 1, true);
    body(nn + 5, S0, 1, 0, true);
  }
  body(54, S1, 0, 1, true);
  body(55, S2, 1, 0, true);
  body(56, S3, 0, 1, true);
  body(57, S4, 1, 0, true);
  body(58, S5, 0, 1, true);
  body(59, S0, 1, 0, true);
  body(60, S1, 0, 1, true);
  body(61, S2, 1, 0, true);
  body(62, S3, 0, 1, true);
  body(63, S4, 1, 0, false);            // last block: no staging/prefetch

  // ---- denominator total (each row counted 8x -> *0.125) ----
  float s = Sacc;
  s += dpp_f<DPP_XOR1>(s);
  s += dpp_f<DPP_XOR2>(s);
  s += dpp_f<DPP_HMIRR>(s);
  s += dpp_f<DPP_MIRR>(s);
  s += __shfl_xor(s, 16, 64);
  s += __shfl_xor(s, 32, 64);
  const float Stot = s * 0.125f;

  // loss = ln2 * (S - (log2(A159+A160) - E));  lane 53: A0=s159, A1=s160
  if (lane == 53) {
    const float lse2 = LOG2F(A0 + A1) - (float)E;
    out[b] = LN2_ * (Stot - lse2);
  }
}

extern "C" void kernel_launch(void* const* d_in, const int* in_sizes, int n_in,
                              void* d_out, int out_size, void* d_ws, size_t ws_size,
                              hipStream_t stream) {
  const int*   labels = (const int*)d_in[0];    // y_true [B,L]
  const float* y_pred = (const float*)d_in[1];  // y_pred [B,T,C]
  float*       out    = (float*)d_out;          // [B,1]
  ctc_fused<<<dim3(B_), dim3(64), 0, stream>>>(labels, y_pred, out);
}